// Round 7
// baseline (763.354 us; speedup 1.0000x reference)
//
#include <hip/hip_runtime.h>

// Problem constants (B=8, C=64, W=496, H=432)
#define WH      214272            // 496*432 pixels per (b,c) plane
#define GPB     53568             // WH/4 float4 groups per plane (mult of 64)
#define TOTAL4  (512*GPB)         // all float4 elements = 27,426,816
#define CHUNKS  (TOTAL4/64)       // 64-float4 (1 KB/wave) chunks = 428544
#define CPP     (GPB/64)          // chunks per plane = 837

#define BLOCKS  2048              // 8 blocks/CU -> 32 waves/CU
#define PER     53                // chunks per wave
#define BPB     (4*PER)           // 212 contiguous chunks per block (spans <=2 planes)

#define NREP    16                // accumulator replicas (atomic de-contention, R4-proven)
// ws layout (floats): gsum[NREP][64] @0, gsq[NREP][64] @1024, gn[8][8] ints @2048
#define WS_FLOATS (NREP*64*2 + 64)

typedef float floatx4 __attribute__((ext_vector_type(4)));

// Forward 6-deep pipelined accumulate over j in [jlo,jhi), chunk stride 4 (1 KB chunks,
// wave's j-th chunk at p + j*4KB). All plain loads.
__device__ __forceinline__ void sweep4(const floatx4* __restrict__ p, int jlo, int jhi,
                                       float& s0, float& s1, float& s2, float& s3,
                                       float& q0, float& q1, float& q2, float& q3,
                                       int& cnt, const bool isC0) {
    int j = jlo;
    for (; j + 6 <= jhi; j += 6) {
        const floatx4 v0 = p[(size_t)(j + 0) * 256];
        const floatx4 v1 = p[(size_t)(j + 1) * 256];
        const floatx4 v2 = p[(size_t)(j + 2) * 256];
        const floatx4 v3 = p[(size_t)(j + 3) * 256];
        const floatx4 v4 = p[(size_t)(j + 4) * 256];
        const floatx4 v5 = p[(size_t)(j + 5) * 256];
        s0 += (v0.x + v0.y) + (v0.z + v0.w);
        s1 += (v1.x + v1.y) + (v1.z + v1.w);
        s2 += (v2.x + v2.y) + (v2.z + v2.w);
        s3 += (v3.x + v3.y) + (v3.z + v3.w);
        q0 = fmaf(v0.w, v0.w, fmaf(v0.z, v0.z, fmaf(v0.y, v0.y, fmaf(v0.x, v0.x, q0))));
        q1 = fmaf(v1.w, v1.w, fmaf(v1.z, v1.z, fmaf(v1.y, v1.y, fmaf(v1.x, v1.x, q1))));
        q2 = fmaf(v2.w, v2.w, fmaf(v2.z, v2.z, fmaf(v2.y, v2.y, fmaf(v2.x, v2.x, q2))));
        q3 = fmaf(v3.w, v3.w, fmaf(v3.z, v3.z, fmaf(v3.y, v3.y, fmaf(v3.x, v3.x, q3))));
        s0 += (v4.x + v4.y) + (v4.z + v4.w);
        s1 += (v5.x + v5.y) + (v5.z + v5.w);
        q0 = fmaf(v4.w, v4.w, fmaf(v4.z, v4.z, fmaf(v4.y, v4.y, fmaf(v4.x, v4.x, q0))));
        q1 = fmaf(v5.w, v5.w, fmaf(v5.z, v5.z, fmaf(v5.y, v5.y, fmaf(v5.x, v5.x, q1))));
        if (isC0) {
            cnt += (v0.x != 0.f) + (v0.y != 0.f) + (v0.z != 0.f) + (v0.w != 0.f);
            cnt += (v1.x != 0.f) + (v1.y != 0.f) + (v1.z != 0.f) + (v1.w != 0.f);
            cnt += (v2.x != 0.f) + (v2.y != 0.f) + (v2.z != 0.f) + (v2.w != 0.f);
            cnt += (v3.x != 0.f) + (v3.y != 0.f) + (v3.z != 0.f) + (v3.w != 0.f);
            cnt += (v4.x != 0.f) + (v4.y != 0.f) + (v4.z != 0.f) + (v4.w != 0.f);
            cnt += (v5.x != 0.f) + (v5.y != 0.f) + (v5.z != 0.f) + (v5.w != 0.f);
        }
    }
    for (; j < jhi; ++j) {
        const floatx4 v = p[(size_t)j * 256];
        s0 += (v.x + v.y) + (v.z + v.w);
        q0 = fmaf(v.w, v.w, fmaf(v.z, v.z, fmaf(v.y, v.y, fmaf(v.x, v.x, q0))));
        if (isC0) cnt += (v.x != 0.f) + (v.y != 0.f) + (v.z != 0.f) + (v.w != 0.f);
    }
}

// ---------------- K1: per-channel sum/sumsq + per-batch mask count ----------------
// Change vs R6 (single variable, k_stats stuck at ~142us = 3.1 TB/s read; occupancy
// and NT/plain partition both proven irrelevant):
//  BLOCK-COOPERATIVE CONTIGUOUS STREAMS, ALL-PLAIN LOADS. Block b owns chunks
//  [212b, 212b+212); its 4 waves interleave at chunk granularity (wave w takes
//  chunks bs+w, bs+w+4, ...). Each block-step consumes a contiguous 4KB window ->
//  2048 wide sequential streams at DRAM instead of 8192 narrow 1KB-step streams.
//  Tests the hypothesis that the read wall is DRAM/row-buffer stream structure
//  (and removes R6's NT front-sweep, which may throttle the read path via L2 bypass).
// Block spans <=2 planes (212 < 837) -> per-wave two plane-segments, channel
// wave-uniform within each. 16 waves share a plane -> replicas absorb atomics.
__global__ __launch_bounds__(256, 8) void k_stats(const floatx4* __restrict__ x4,
                                                  float* __restrict__ gsum,
                                                  float* __restrict__ gsq,
                                                  int* __restrict__ gn) {
    const int lane = threadIdx.x & 63;
    const int w    = threadIdx.x >> 6;            // wave within block
    const int gw   = blockIdx.x * 4 + w;
    const int rep  = gw & (NREP - 1);
    const int bs   = blockIdx.x * BPB;
    const int be   = min(bs + BPB, CHUNKS);
    const int start = bs + w;                     // this wave's first chunk
    if (start >= be) return;
    const int nj = ((be - start) + 3) >> 2;       // this wave's chunk count (stride 4)

    const int pA = (int)((unsigned)bs / CPP);     // block's first plane
    const int cB = (pA + 1) * CPP;                // first chunk of next plane
    int jb = (cB <= start) ? 0 : ((cB - start + 3) >> 2);   // first j in plane pA+1
    if (jb > nj) jb = nj;

    const floatx4* p = x4 + (size_t)start * 64 + lane;

#pragma unroll
    for (int seg = 0; seg < 2; ++seg) {
        const int jlo = seg ? jb : 0;
        const int jhi = seg ? nj : jb;
        if (jlo >= jhi) continue;
        const int plane = pA + seg;               // wave-uniform
        const bool isC0 = (plane & 63) == 0;

        float s0 = 0.f, s1 = 0.f, s2 = 0.f, s3 = 0.f;
        float q0 = 0.f, q1 = 0.f, q2 = 0.f, q3 = 0.f;
        int cnt = 0;
        sweep4(p, jlo, jhi, s0, s1, s2, s3, q0, q1, q2, q3, cnt, isC0);

        float ss = (s0 + s1) + (s2 + s3);
        float qq = (q0 + q1) + (q2 + q3);
#pragma unroll
        for (int m = 1; m < 64; m <<= 1) {
            ss += __shfl_xor(ss, m, 64);
            qq += __shfl_xor(qq, m, 64);
        }
        if (isC0) {
#pragma unroll
            for (int m = 1; m < 64; m <<= 1) cnt += __shfl_xor(cnt, m, 64);
        }
        if (lane == 0) {
            atomicAdd(&gsum[rep * 64 + (plane & 63)], ss);
            atomicAdd(&gsq[rep * 64 + (plane & 63)], qq);
            if (isC0) atomicAdd(&gn[(rep & 7) * 8 + (plane >> 6)], cnt);
        }
    }
}

// ---------------- K2: finalize (prologue) + out = x * inv[c], MIRRORED reverse ------
// BYTE-IDENTICAL to R2/R4 (proven at its ~438MB NT-write floor, ~66us apparent).
// NT load/store: R3 proved plain stores regress (they evict x's L3 residency).
__global__ __launch_bounds__(256, 8) void k_scale(const floatx4* __restrict__ x4,
                                                  floatx4* __restrict__ out4,
                                                  const float* __restrict__ gsum,
                                                  const float* __restrict__ gsq,
                                                  const int* __restrict__ gn) {
    __shared__ float sinv[64];
    const int tid = threadIdx.x;
    if (tid < 64) {
        const int c = tid;
        const float* x = (const float*)x4;
        float total = 0.f, S2 = 0.f;
#pragma unroll
        for (int r = 0; r < NREP; ++r) {
            total += gsum[r * 64 + c];
            S2    += gsq[r * 64 + c];
        }
        int nb[8];
        int N = 0;
#pragma unroll
        for (int b = 0; b < 8; ++b) {
            int v = 0;
#pragma unroll
            for (int r = 0; r < 8; ++r) v += gn[r * 8 + b];
            nb[b] = v;
            N = max(N, v);
        }
#pragma unroll
        for (int b = 0; b < 8; ++b) {
            const float pad = (float)(N - nb[b]);
            const float x00 = x[(size_t)(b * 64 + c) * WH];
            total = fmaf(pad, x00, total);
            S2    = fmaf(pad, x00 * x00, S2);
        }
        const float count = (float)(8 * N);
        const float mean  = total / count;
        const float var   = S2 / count - mean * mean;
        sinv[c] = 1.0f / sqrtf(var + 0.001f);
    }
    __syncthreads();

    const int lane = tid & 63;
    const int gw   = blockIdx.x * 4 + (tid >> 6);   // 0..8191
    const int c0   = gw * PER;
    const int c1   = min(c0 + PER, CHUNKS);
#pragma unroll 4
    for (int ch = c1 - 1; ch >= c0; --ch) {
        const int plane = (int)((unsigned)ch / CPP);      // wave-uniform
        const float inv = sinv[plane & 63];
        const size_t i = (size_t)ch * 64 + lane;
        floatx4 v = __builtin_nontemporal_load(&x4[i]);
        v.x *= inv; v.y *= inv; v.z *= inv; v.w *= inv;
        __builtin_nontemporal_store(v, &out4[i]);
    }
}

extern "C" void kernel_launch(void* const* d_in, const int* in_sizes, int n_in,
                              void* d_out, int out_size, void* d_ws, size_t ws_size,
                              hipStream_t stream) {
    const float* x  = (const float*)d_in[0];
    float* out      = (float*)d_out;
    float* wsf      = (float*)d_ws;
    float* gsum     = wsf;                        // [NREP][64]
    float* gsq      = wsf + NREP * 64;            // [NREP][64]
    int*   gn       = (int*)(wsf + NREP * 128);   // [8][8]

    (void)hipMemsetAsync(d_ws, 0, WS_FLOATS * sizeof(float), stream);

    k_stats<<<BLOCKS, 256, 0, stream>>>((const floatx4*)x, gsum, gsq, gn);
    k_scale<<<BLOCKS, 256, 0, stream>>>((const floatx4*)x, (floatx4*)out,
                                        gsum, gsq, gn);
}